// Round 3
// baseline (103.044 us; speedup 1.0000x reference)
//
#include <hip/hip_runtime.h>
#include <math.h>

#define NG 1024
#define HH 256
#define WW 256
#define TILE_PX 64
#define WT 4
#define FOCAL_F 256.0f      // W / (2 * TAN_FOV)
#define RADII_MULT_F 5.0f

// ws layout (floats), sorted by depth rank:
//   [0, 4*NG)        : rect  float4 per gaussian  (rminx, rmaxx, rminy, rmaxy)
//   [4*NG, 12*NG)    : attrs 2x float4 per gaussian:
//                        A = (m2x, m2y, kexp, op), B = (r, g, b, dep)

__global__ __launch_bounds__(64) void prep_rank_kernel(
    const float* __restrict__ means3d, const float* __restrict__ opacity,
    const float* __restrict__ scale3d, const float* __restrict__ features,
    const float* __restrict__ viewm, const float* __restrict__ projm,
    float* __restrict__ ws)
{
    __shared__ float s_dep[NG];

    const int l = threadIdx.x;
    const int gid = blockIdx.x * 64 + l;

    const float v2 = viewm[2], v6 = viewm[6], v10 = viewm[10], v14 = viewm[14];

    // each lane computes depths for 16 gaussians (block-redundant, 16 CUs)
#pragma unroll
    for (int c = 0; c < NG / 64; c++) {
        const int g = c * 64 + l;
        const float mx = means3d[g * 3 + 0];
        const float my = means3d[g * 3 + 1];
        const float mz = means3d[g * 3 + 2];
        s_dep[g] = mx * v2 + my * v6 + mz * v10 + v14;
    }
    __syncthreads();

    // rank of my gaussian (stable argsort semantics), float4-vectorized scan
    const float myd = s_dep[gid];
    const float4* sd4 = (const float4*)s_dep;
    int rank = 0;
#pragma unroll 8
    for (int j4 = 0; j4 < NG / 4; j4++) {
        const float4 d = sd4[j4];
        const int jb = j4 * 4;
        rank += (d.x < myd || (d.x == myd && jb + 0 < gid)) ? 1 : 0;
        rank += (d.y < myd || (d.y == myd && jb + 1 < gid)) ? 1 : 0;
        rank += (d.z < myd || (d.z == myd && jb + 2 < gid)) ? 1 : 0;
        rank += (d.w < myd || (d.w == myd && jb + 3 < gid)) ? 1 : 0;
    }

    // full attributes for my gaussian
    float V[16], P[16];
#pragma unroll
    for (int j = 0; j < 16; j++) { V[j] = viewm[j]; P[j] = projm[j]; }

    const float mx = means3d[gid * 3 + 0];
    const float my = means3d[gid * 3 + 1];
    const float mz = means3d[gid * 3 + 2];

    const float q0 = mx * V[0] + my * V[4] + mz * V[8]  + V[12];
    const float q1 = mx * V[1] + my * V[5] + mz * V[9]  + V[13];
    const float q2 = mx * V[2] + my * V[6] + mz * V[10] + V[14];
    const float q3 = mx * V[3] + my * V[7] + mz * V[11] + V[15];
    const float h0 = q0 * P[0] + q1 * P[4] + q2 * P[8]  + q3 * P[12];
    const float h1 = q0 * P[1] + q1 * P[5] + q2 * P[9]  + q3 * P[13];
    const float h3 = q0 * P[3] + q1 * P[7] + q2 * P[11] + q3 * P[15];

    const float inv_w = 1.0f / (h3 + 1e-6f);
    const float m2x = ((h0 * inv_w + 1.0f) * (float)WW - 1.0f) * 0.5f;
    const float m2y = ((h1 * inv_w + 1.0f) * (float)HH - 1.0f) * 0.5f;

    const float s2 = scale3d[gid] * FOCAL_F / q2;
    const float radii = s2 * RADII_MULT_F;
    const float kexp = -0.72134752044448170f / (s2 * s2);  // -0.5*log2(e)/s2sq

    float4 rect;
    rect.x = fminf(fmaxf(m2x - radii, 0.0f), (float)(WW - 1));  // rminx
    rect.y = fminf(fmaxf(m2x + radii, 0.0f), (float)(WW - 1));  // rmaxx
    rect.z = fminf(fmaxf(m2y - radii, 0.0f), (float)(HH - 1));  // rminy
    rect.w = fminf(fmaxf(m2y + radii, 0.0f), (float)(HH - 1));  // rmaxy

    float4 attrA = make_float4(m2x, m2y, kexp, opacity[gid]);
    float4 attrB = make_float4(features[gid * 3 + 0], features[gid * 3 + 1],
                               features[gid * 3 + 2], q2);

    ((float4*)ws)[rank] = rect;
    float4* attrs = (float4*)(ws + 4 * NG);
    attrs[rank * 2 + 0] = attrA;
    attrs[rank * 2 + 1] = attrB;
}

// one wave per pixel row-of-tile: 1024 blocks = 16 tiles x 64 rows
__global__ __launch_bounds__(64) void render_kernel(
    const float* __restrict__ ws, float* __restrict__ out)
{
    __shared__ float4 s_listA[NG];   // m2x m2y k op
    __shared__ float4 s_listB[NG];   // r g b dep

    const int tile = blockIdx.x >> 6;        // 16 tiles
    const int row  = blockIdx.x & 63;        // row within tile
    const int u0 = (tile % WT) * TILE_PX;
    const int v0 = (tile / WT) * TILE_PX;
    const int l = threadIdx.x;
    const int pxi = u0 + l;
    const int pyi = v0 + row;
    const float px = (float)pxi;
    const float py = (float)pyi;
    const float u0f = (float)u0;
    const float u1f = (float)(u0 + TILE_PX - 1);

    const float4* rects = (const float4*)ws;
    const float4* attrs = (const float4*)(ws + 4 * NG);

    // ---- ballot-compact gaussians relevant to this row (order-preserving) ----
    int cnt = 0;
    for (int base = 0; base < NG; base += 64) {
        const int g = base + l;
        const float4 rc = rects[g];   // rminx rmaxx rminy rmaxy
        const bool pass = (fminf(rc.y, u1f) > fmaxf(rc.x, u0f)) &&
                          (rc.z <= py) && (py <= rc.w);
        const unsigned long long m = __ballot(pass);
        if (pass) {
            const int off = cnt + __popcll(m & ((1ull << l) - 1ull));
            s_listA[off] = attrs[g * 2 + 0];
            s_listB[off] = attrs[g * 2 + 1];
        }
        cnt += __popcll(m);
    }
    __syncthreads();   // single wave: orders LDS writes before reads

    // ---- front-to-back blend over compacted list (broadcast LDS reads) ----
    float T = 1.0f, cr = 0.0f, cg = 0.0f, cb = 0.0f, dsum = 0.0f, accsum = 0.0f;
    for (int e = 0; e < cnt; e++) {
        const float4 a = s_listA[e];
        const float4 b = s_listB[e];
        const float dx = px - a.x;
        const float dy = py - a.y;
        const float d2 = dx * dx + dy * dy;
        const float gw = exp2f(d2 * a.z);
        const float alpha = fminf(gw * a.w, 0.99f);
        const float w = alpha * T;
        cr += w * b.x;
        cg += w * b.y;
        cb += w * b.z;
        dsum += w * b.w;
        accsum += w;
        T -= alpha * T;
    }

    const float bg = 1.0f - accsum;
    cr = fminf(fmaxf(cr + bg, 0.0f), 1.0f);
    cg = fminf(fmaxf(cg + bg, 0.0f), 1.0f);
    cb = fminf(fmaxf(cb + bg, 0.0f), 1.0f);

    const int pix = pyi * WW + pxi;
    out[pix * 3 + 0] = cr;
    out[pix * 3 + 1] = cg;
    out[pix * 3 + 2] = cb;
    out[WW * HH * 3 + pix] = dsum;
    out[WW * HH * 4 + pix] = accsum;
}

extern "C" void kernel_launch(void* const* d_in, const int* in_sizes, int n_in,
                              void* d_out, int out_size, void* d_ws, size_t ws_size,
                              hipStream_t stream) {
    const float* means3d  = (const float*)d_in[0];
    const float* opacity  = (const float*)d_in[1];
    const float* scale3d  = (const float*)d_in[2];
    const float* features = (const float*)d_in[3];
    const float* viewm    = (const float*)d_in[4];
    const float* projm    = (const float*)d_in[5];
    float* ws  = (float*)d_ws;
    float* out = (float*)d_out;

    prep_rank_kernel<<<16, 64, 0, stream>>>(means3d, opacity, scale3d, features,
                                            viewm, projm, ws);
    render_kernel<<<1024, 64, 0, stream>>>(ws, out);
}